// Round 7
// baseline (543.360 us; speedup 1.0000x reference)
//
#include <hip/hip_runtime.h>

// Attention block: x_s = softmax(qk^T)[:4096,4096:] @ query @ Wps^T
//                  x_q = softmax(qk^T)[4096:,:4096] @ s     @ Wpq^T
// R7: all GEMMs moved to v_mfma_f32_32x32x16_bf16 (16 MFMA/K-tile @8cyc vs
// 32 @4.85 — m119: +15% ceiling, half the MFMA insts). k-slot mapping of A/B
// frags is correctness-invariant (same permutation both operands); C/D layout
// col=lane&31, row=(reg&3)+8*(reg>>2)+4*(lane>>5) is HW-verified (m74/m101).
// EPI1 back to direct scalar stores (R6's LDS transpose regressed: DS tail
// serialization, 2.6e5 conflicts). Keeps R6's re-association:
// (P@query)@Wps^T = P@(Wps@query^T)^T — V'^T precomputed, PV writes d_out.
// XOR-swizzled LDS staging (R3: conflicts 0), hoisted frag offsets (R5).

typedef unsigned short u16;
typedef __bf16 bf16x8 __attribute__((ext_vector_type(8)));
typedef float f32x16 __attribute__((ext_vector_type(16)));
typedef unsigned short u16x8 __attribute__((ext_vector_type(8)));

#define DEVI static __device__ __forceinline__

DEVI u16 f2b(float f) {  // fp32 -> bf16 round-to-nearest-even
  unsigned int u = __float_as_uint(f);
  u += 0x7fffu + ((u >> 16) & 1u);
  return (u16)(u >> 16);
}

DEVI float exp2_hw(float x) {  // v_exp_f32: 2^x
  float r;
  asm("v_exp_f32 %0, %1" : "=v"(r) : "v"(x));
  return r;
}

// ---------------- prep kernels ----------------

// cB (8192x1024): rows 0..4095 = bf16(s+TG), rows 4096.. = bf16(query).
// sBf (4096x1024) = bf16(s).
__global__ void prep_c(const float* __restrict__ query, const float* __restrict__ s,
                       const float* __restrict__ tg, u16* __restrict__ cB,
                       u16* __restrict__ sBf) {
  int base = (blockIdx.x * 256 + threadIdx.x) << 3;
  int row = base >> 10;
  u16x8 o;
  if (row < 4096) {
    float4 a0 = *(const float4*)(s + base);
    float4 a1 = *(const float4*)(s + base + 4);
    float4 b0 = *(const float4*)(tg + base);
    float4 b1 = *(const float4*)(tg + base + 4);
    u16x8 os;
    os[0] = f2b(a0.x); os[1] = f2b(a0.y); os[2] = f2b(a0.z); os[3] = f2b(a0.w);
    os[4] = f2b(a1.x); os[5] = f2b(a1.y); os[6] = f2b(a1.z); os[7] = f2b(a1.w);
    *(u16x8*)(sBf + base) = os;
    o[0] = f2b(a0.x + b0.x); o[1] = f2b(a0.y + b0.y);
    o[2] = f2b(a0.z + b0.z); o[3] = f2b(a0.w + b0.w);
    o[4] = f2b(a1.x + b1.x); o[5] = f2b(a1.y + b1.y);
    o[6] = f2b(a1.z + b1.z); o[7] = f2b(a1.w + b1.w);
  } else {
    int qb = base - 4096 * 1024;
    float4 a0 = *(const float4*)(query + qb);
    float4 a1 = *(const float4*)(query + qb + 4);
    o[0] = f2b(a0.x); o[1] = f2b(a0.y); o[2] = f2b(a0.z); o[3] = f2b(a0.w);
    o[4] = f2b(a1.x); o[5] = f2b(a1.y); o[6] = f2b(a1.z); o[7] = f2b(a1.w);
  }
  *(u16x8*)(cB + base) = o;
}

// 3 weight conversions: blocks [0,1024) Wqkv(q,k rows), [1024,1536) Wps, rest Wpq
__global__ void conv3(const float* __restrict__ w0, const float* __restrict__ w1,
                      const float* __restrict__ w2, u16* __restrict__ o0,
                      u16* __restrict__ o1, u16* __restrict__ o2) {
  int b = blockIdx.x;
  const float* in; u16* out; int lb;
  if (b < 1024)      { in = w0; out = o0; lb = b; }
  else if (b < 1536) { in = w1; out = o1; lb = b - 1024; }
  else               { in = w2; out = o2; lb = b - 1536; }
  int base = (lb * 256 + threadIdx.x) << 3;
  float4 a0 = *(const float4*)(in + base);
  float4 a1 = *(const float4*)(in + base + 4);
  u16x8 o;
  o[0] = f2b(a0.x); o[1] = f2b(a0.y); o[2] = f2b(a0.z); o[3] = f2b(a0.w);
  o[4] = f2b(a1.x); o[5] = f2b(a1.y); o[6] = f2b(a1.z); o[7] = f2b(a1.w);
  *(u16x8*)(out + base) = o;
}

// ---------------- 128x128-tile GEMM, 4 waves, 32x32x16 MFMA ----------------
// C[M,N] = A[M,K] @ B[N,K]^T. Wave tile 64x64 = 2x2 tiles of 32x32.
// EPI 0: outb = bf16(acc * (col<1024 ? sq : sk))      (q|k projection)
// EPI 1: 2^acc, quadrant scalar store, rowsum atomics  (scores)
// EPI 4: outf = acc / rs[row]  (fp32, z-batched)       (PV -> d_out)
// EPI 5: outb = bf16(acc)      (z-batched)             (V'^T = Wproj@input^T)

template <int EPI>
__global__ __launch_bounds__(256)
void gemm_bt(const u16* __restrict__ A, const u16* __restrict__ A1,
             const u16* __restrict__ B, const u16* __restrict__ B1,
             int lda, int ldb, int K, int ldc,
             u16* __restrict__ outb, u16* __restrict__ outb1,
             float* __restrict__ outf, float* __restrict__ outf1,
             float sq, float sk,
             const float* __restrict__ rs, const float* __restrict__ rs1,
             u16* __restrict__ Pcq, u16* __restrict__ Pqc,
             float* __restrict__ rowsum) {
  __shared__ __align__(16) u16 sA[128 * 64];
  __shared__ __align__(16) u16 sB[128 * 64];
  const int tid = threadIdx.x;
  const int lane = tid & 63;
  const int wave = tid >> 6;
  const int wr = (wave >> 1) * 64;
  const int wc = (wave & 1) * 64;
  const int by = blockIdx.y, bx = blockIdx.x;
  const int z = blockIdx.z;

  const u16* Ab = (z ? A1 : A) + (size_t)(by * 128) * lda;
  const u16* Bb = (z ? B1 : B) + (size_t)(bx * 128) * ldb;

  f32x16 acc[2][2];
#pragma unroll
  for (int i = 0; i < 2; ++i)
#pragma unroll
    for (int j = 0; j < 2; ++j)
#pragma unroll
      for (int e = 0; e < 16; ++e) acc[i][j][e] = 0.0f;

  const int sr = tid >> 3;                        // 0..31 (row within 32-row group)
  const int scL = (tid & 7) << 3;                 // LDS dst col (lane*16B forced)
  const int scG = ((tid & 7) ^ (sr & 7)) << 3;    // swizzled global col granule

  // 32x32x16 fragment addressing: lane holds m = lane&31, k-granule gl0 = lane>>5.
  // Physical granule = (gl0 ^ (kk>>3)) ^ (row&7); row&7 == lane&7.
  // kk in {0,16,32,48} -> XOR byte offsets {0,32,64,96} (granule bits 1,2).
  const int m31 = lane & 31;
  const int gbase = ((lane >> 5) ^ (lane & 7)) << 4;
  const int offA0 = (wr + m31) * 128 + gbase;     // + tm*4096 (32 rows)
  const int offB0 = (wc + m31) * 128 + gbase;
  const char* sAc = (const char*)sA;
  const char* sBc = (const char*)sB;

  for (int k0 = 0; k0 < K; k0 += 64) {
#pragma unroll
    for (int it = 0; it < 4; ++it) {
      int r = it * 32 + sr;
      __builtin_amdgcn_global_load_lds(
          (__attribute__((address_space(1))) void*)(Ab + (size_t)r * lda + k0 + scG),
          (__attribute__((address_space(3))) void*)(sA + r * 64 + scL), 16, 0, 0);
    }
#pragma unroll
    for (int it = 0; it < 4; ++it) {
      int r = it * 32 + sr;
      __builtin_amdgcn_global_load_lds(
          (__attribute__((address_space(1))) void*)(Bb + (size_t)r * ldb + k0 + scG),
          (__attribute__((address_space(3))) void*)(sB + r * 64 + scL), 16, 0, 0);
    }
    __syncthreads();
#pragma unroll
    for (int kk = 0; kk < 64; kk += 16) {
      const int kx = kk << 1;  // {0,32,64,96}
      bf16x8 a0 = *(const bf16x8*)(sAc + ((offA0 ^ kx)));
      bf16x8 a1 = *(const bf16x8*)(sAc + ((offA0 ^ kx) + 4096));
      bf16x8 b0 = *(const bf16x8*)(sBc + ((offB0 ^ kx)));
      bf16x8 b1 = *(const bf16x8*)(sBc + ((offB0 ^ kx) + 4096));
      acc[0][0] = __builtin_amdgcn_mfma_f32_32x32x16_bf16(a0, b0, acc[0][0], 0, 0, 0);
      acc[0][1] = __builtin_amdgcn_mfma_f32_32x32x16_bf16(a0, b1, acc[0][1], 0, 0, 0);
      acc[1][0] = __builtin_amdgcn_mfma_f32_32x32x16_bf16(a1, b0, acc[1][0], 0, 0, 0);
      acc[1][1] = __builtin_amdgcn_mfma_f32_32x32x16_bf16(a1, b1, acc[1][1], 0, 0, 0);
    }
    __syncthreads();
  }

  // Epilogue. 32x32 C/D layout (m74/m101): col = lane&31,
  // row = (reg&3) + 8*(reg>>2) + 4*(lane>>5).
  const int cloc = lane & 31;
  const int rq = (lane >> 5) * 4;

  if constexpr (EPI == 0) {
#pragma unroll
    for (int tm = 0; tm < 2; ++tm)
#pragma unroll
      for (int i = 0; i < 16; ++i) {
        int row = by * 128 + wr + tm * 32 + (i & 3) + 8 * (i >> 2) + rq;
#pragma unroll
        for (int tn = 0; tn < 2; ++tn) {
          int col = bx * 128 + wc + tn * 32 + cloc;
          float sc = (col < 1024) ? sq : sk;
          outb[(size_t)row * ldc + col] = f2b(acc[tm][tn][i] * sc);
        }
      }
  } else if constexpr (EPI == 1) {
    const bool top = (by < 32);
    const bool left = (bx < 32);
    u16* pdst = nullptr;
    if (top && !left) pdst = Pcq;
    if (!top && left) pdst = Pqc;
    const int growb = by * 128 + wr;             // global row base of wave
    const int rbase = growb - (top ? 0 : 4096);  // quadrant-local
    const int cbase = bx * 128 + wc - (left ? 0 : 4096) + cloc;
#pragma unroll
    for (int tm = 0; tm < 2; ++tm) {
      float e[2][16];
      float rsum[16];
#pragma unroll
      for (int i = 0; i < 16; ++i) rsum[i] = 0.f;
#pragma unroll
      for (int tn = 0; tn < 2; ++tn)
#pragma unroll
        for (int i = 0; i < 16; ++i) {
          e[tn][i] = exp2_hw(acc[tm][tn][i]);  // scores pre-scaled by log2(e)
          rsum[i] += e[tn][i];
        }
#pragma unroll
      for (int i = 0; i < 16; ++i) {
        float v = rsum[i];
        v += __shfl_xor(v, 1);
        v += __shfl_xor(v, 2);
        v += __shfl_xor(v, 4);
        v += __shfl_xor(v, 8);
        v += __shfl_xor(v, 16);
        if (cloc == 0)
          atomicAdd(&rowsum[growb + tm * 32 + (i & 3) + 8 * (i >> 2) + rq], v);
      }
      if (pdst) {
#pragma unroll
        for (int tn = 0; tn < 2; ++tn)
#pragma unroll
          for (int i = 0; i < 16; ++i) {
            int row = rbase + tm * 32 + (i & 3) + 8 * (i >> 2) + rq;
            pdst[(size_t)row * 4096 + cbase + tn * 32] = f2b(e[tn][i]);
          }
      }
    }
  } else if constexpr (EPI == 4) {
    float* of = z ? outf1 : outf;
    const float* rsz = z ? rs1 : rs;
#pragma unroll
    for (int tm = 0; tm < 2; ++tm)
#pragma unroll
      for (int i = 0; i < 16; ++i) {
        int row = by * 128 + wr + tm * 32 + (i & 3) + 8 * (i >> 2) + rq;
        float inv = 1.0f / rsz[row];
#pragma unroll
        for (int tn = 0; tn < 2; ++tn) {
          int col = bx * 128 + wc + tn * 32 + cloc;
          of[(size_t)row * ldc + col] = acc[tm][tn][i] * inv;
        }
      }
  } else {  // EPI 5
    u16* ob = z ? outb1 : outb;
#pragma unroll
    for (int tm = 0; tm < 2; ++tm)
#pragma unroll
      for (int i = 0; i < 16; ++i) {
        int row = by * 128 + wr + tm * 32 + (i & 3) + 8 * (i >> 2) + rq;
#pragma unroll
        for (int tn = 0; tn < 2; ++tn) {
          int col = bx * 128 + wc + tn * 32 + cloc;
          ob[(size_t)row * ldc + col] = f2b(acc[tm][tn][i]);
        }
      }
  }
}

// ---------------- launcher ----------------

extern "C" void kernel_launch(void* const* d_in, const int* in_sizes, int n_in,
                              void* d_out, int out_size, void* d_ws, size_t ws_size,
                              hipStream_t stream) {
  (void)in_sizes; (void)n_in; (void)out_size; (void)ws_size;
  const float* query = (const float*)d_in[0];
  const float* s     = (const float*)d_in[1];
  const float* tg    = (const float*)d_in[2];
  const float* Wqkv  = (const float*)d_in[3];
  const float* Wps   = (const float*)d_in[4];
  const float* Wpq   = (const float*)d_in[5];
  float* out = (float*)d_out;

  char* ws = (char*)d_ws;
  u16* cB     = (u16*)ws; ws += (size_t)8192 * 1024 * 2;   // [s+tg ; query] bf16
  u16* sBf    = (u16*)ws; ws += (size_t)4096 * 1024 * 2;   // s bf16
  u16* qks    = (u16*)ws; ws += (size_t)8192 * 2048 * 2;   // [q*SCALE*LOG2E | k*SCALE]
  u16* WqkB   = (u16*)ws; ws += (size_t)2048 * 1024 * 2;
  u16* WpsB   = (u16*)ws; ws += (size_t)1024 * 1024 * 2;
  u16* WpqB   = (u16*)ws; ws += (size_t)1024 * 1024 * 2;
  u16* VsT    = (u16*)ws; ws += (size_t)1024 * 4096 * 2;   // (query@Wps^T)^T
  u16* VqT    = (u16*)ws; ws += (size_t)1024 * 4096 * 2;   // (s@Wpq^T)^T
  u16* Pcq    = (u16*)ws; ws += (size_t)4096 * 4096 * 2;
  u16* Pqc    = (u16*)ws; ws += (size_t)4096 * 4096 * 2;
  float* rowsum = (float*)ws;  // 8192 floats

  const u16* qBf = cB + (size_t)4096 * 1024;  // query bf16 rows of cB

  const float SCALE = 0.17677669529663687f;   // 1024^-0.25
  const float LOG2E = 1.4426950408889634f;

  (void)hipMemsetAsync(rowsum, 0, 8192 * sizeof(float), stream);
  prep_c<<<4096, 256, 0, stream>>>(query, s, tg, cB, sBf);
  conv3<<<2048, 256, 0, stream>>>(Wqkv, Wps, Wpq, WqkB, WpsB, WpqB);

  // V'^T pair: VsT = Wps@query^T, VqT = Wpq@s^T  (M=1024,N=4096,K=1024)
  gemm_bt<5><<<dim3(32, 8, 2), 256, 0, stream>>>(
      WpsB, WpqB, qBf, sBf, 1024, 1024, 1024, 4096,
      VsT, VqT, nullptr, nullptr, 0.f, 0.f,
      nullptr, nullptr, nullptr, nullptr, nullptr);
  // GEMM1: qks[8192,2048] = cB @ WqkB^T; q cols scaled SCALE*LOG2E, k cols SCALE
  gemm_bt<0><<<dim3(16, 64), 256, 0, stream>>>(
      cB, nullptr, WqkB, nullptr, 1024, 1024, 1024, 2048,
      qks, nullptr, nullptr, nullptr, SCALE * LOG2E, SCALE,
      nullptr, nullptr, nullptr, nullptr, nullptr);
  // GEMM2: scores (8192x8192) -> 2^score quadrants (bf16) + row sums
  gemm_bt<1><<<dim3(64, 64), 256, 0, stream>>>(
      qks, nullptr, qks + 1024, nullptr, 2048, 2048, 1024, 0,
      nullptr, nullptr, nullptr, nullptr, 0.f, 0.f,
      nullptr, nullptr, Pcq, Pqc, rowsum);
  // PV (z-batched), fp32 straight to d_out: x_s = (Pcq@V's)/rs ; x_q = (Pqc@V'q)/rs
  gemm_bt<4><<<dim3(8, 32, 2), 256, 0, stream>>>(
      Pcq, Pqc, VsT, VqT, 4096, 4096, 4096, 1024,
      nullptr, nullptr, out, out + (size_t)4096 * 1024, 0.f, 0.f,
      rowsum, rowsum + 4096, nullptr, nullptr, nullptr);
}

// Round 8
// 465.706 us; speedup vs baseline: 1.1667x; 1.1667x over previous
//
#include <hip/hip_runtime.h>

// Attention block: x_s = softmax(qk^T)[:4096,4096:] @ query @ Wps^T
//                  x_q = softmax(qk^T)[4096:,:4096] @ s     @ Wpq^T
// R8 = best-known composite:
//  - 16x16x32 bf16 MFMA 128x128/4-wave K-loop, XOR-swizzled LDS staging
//    (R3/R5: SQ_LDS_BANK_CONFLICT == 0; R7's 32x32 path hit 4 conflict
//    cyc/ds_read_b128 -> reverted).
//  - R6 re-association: (P@query)@Wps^T = P@(Wps@query^T)^T. V'^T pair
//    precomputed; PV GEMM divides by rowsum and writes fp32 straight to d_out.
//  - EPI1 direct scalar stores (R6's LDS-transpose epilogue regressed).
//  - exp->2^x fold: LOG2E into GEMM1 q-scale, raw v_exp_f32 in score epilogue.
//  - prep_c + conv3 merged into one launch.

typedef unsigned short u16;
typedef __bf16 bf16x8 __attribute__((ext_vector_type(8)));
typedef float f32x4 __attribute__((ext_vector_type(4)));
typedef unsigned short u16x8 __attribute__((ext_vector_type(8)));

#define DEVI static __device__ __forceinline__

DEVI u16 f2b(float f) {  // fp32 -> bf16 round-to-nearest-even
  unsigned int u = __float_as_uint(f);
  u += 0x7fffu + ((u >> 16) & 1u);
  return (u16)(u >> 16);
}

DEVI float exp2_hw(float x) {  // v_exp_f32: 2^x
  float r;
  asm("v_exp_f32 %0, %1" : "=v"(r) : "v"(x));
  return r;
}

// ---------------- fused prep ----------------
// blocks [0,4096):  cB rows (s+tg | query), plus sBf = bf16(s) for rows<4096
// blocks [4096,5120): Wqkv q,k rows -> WqkB
// blocks [5120,5632): Wps -> WpsB ; [5632,6144): Wpq -> WpqB
__global__ void prep_all(const float* __restrict__ query, const float* __restrict__ s,
                         const float* __restrict__ tg, const float* __restrict__ w0,
                         const float* __restrict__ w1, const float* __restrict__ w2,
                         u16* __restrict__ cB, u16* __restrict__ sBf,
                         u16* __restrict__ o0, u16* __restrict__ o1,
                         u16* __restrict__ o2) {
  int b = blockIdx.x;
  if (b < 4096) {
    int base = (b * 256 + threadIdx.x) << 3;
    int row = base >> 10;
    u16x8 o;
    if (row < 4096) {
      float4 a0 = *(const float4*)(s + base);
      float4 a1 = *(const float4*)(s + base + 4);
      float4 b0 = *(const float4*)(tg + base);
      float4 b1 = *(const float4*)(tg + base + 4);
      u16x8 os;
      os[0] = f2b(a0.x); os[1] = f2b(a0.y); os[2] = f2b(a0.z); os[3] = f2b(a0.w);
      os[4] = f2b(a1.x); os[5] = f2b(a1.y); os[6] = f2b(a1.z); os[7] = f2b(a1.w);
      *(u16x8*)(sBf + base) = os;
      o[0] = f2b(a0.x + b0.x); o[1] = f2b(a0.y + b0.y);
      o[2] = f2b(a0.z + b0.z); o[3] = f2b(a0.w + b0.w);
      o[4] = f2b(a1.x + b1.x); o[5] = f2b(a1.y + b1.y);
      o[6] = f2b(a1.z + b1.z); o[7] = f2b(a1.w + b1.w);
    } else {
      int qb = base - 4096 * 1024;
      float4 a0 = *(const float4*)(query + qb);
      float4 a1 = *(const float4*)(query + qb + 4);
      o[0] = f2b(a0.x); o[1] = f2b(a0.y); o[2] = f2b(a0.z); o[3] = f2b(a0.w);
      o[4] = f2b(a1.x); o[5] = f2b(a1.y); o[6] = f2b(a1.z); o[7] = f2b(a1.w);
    }
    *(u16x8*)(cB + base) = o;
  } else {
    const float* in; u16* out; int lb;
    if (b < 5120)      { in = w0; out = o0; lb = b - 4096; }
    else if (b < 5632) { in = w1; out = o1; lb = b - 5120; }
    else               { in = w2; out = o2; lb = b - 5632; }
    int base = (lb * 256 + threadIdx.x) << 3;
    float4 a0 = *(const float4*)(in + base);
    float4 a1 = *(const float4*)(in + base + 4);
    u16x8 o;
    o[0] = f2b(a0.x); o[1] = f2b(a0.y); o[2] = f2b(a0.z); o[3] = f2b(a0.w);
    o[4] = f2b(a1.x); o[5] = f2b(a1.y); o[6] = f2b(a1.z); o[7] = f2b(a1.w);
    *(u16x8*)(out + base) = o;
  }
}

// ---------------- 128x128-tile GEMM, 4 waves: C[M,N] = A[M,K] @ B[N,K]^T ----
// EPI 0: outb = bf16(acc * (col<1024 ? sq : sk))      (q|k projection)
// EPI 1: 2^acc, quadrant scalar store, rowsum atomics  (scores)
// EPI 4: outf = acc / rs[row]  (fp32, z-batched)       (PV -> d_out)
// EPI 5: outb = bf16(acc)      (z-batched)             (V'^T = Wproj@input^T)

template <int EPI>
__global__ __launch_bounds__(256)
void gemm_bt(const u16* __restrict__ A, const u16* __restrict__ A1,
             const u16* __restrict__ B, const u16* __restrict__ B1,
             int lda, int ldb, int K, int ldc,
             u16* __restrict__ outb, u16* __restrict__ outb1,
             float* __restrict__ outf, float* __restrict__ outf1,
             float sq, float sk,
             const float* __restrict__ rs, const float* __restrict__ rs1,
             u16* __restrict__ Pcq, u16* __restrict__ Pqc,
             float* __restrict__ rowsum) {
  __shared__ __align__(16) u16 sA[128 * 64];
  __shared__ __align__(16) u16 sB[128 * 64];
  const int tid = threadIdx.x;
  const int lane = tid & 63;
  const int wave = tid >> 6;
  const int wr = (wave >> 1) * 64;
  const int wc = (wave & 1) * 64;
  const int ar = lane & 15;
  const int by = blockIdx.y, bx = blockIdx.x;
  const int z = blockIdx.z;

  const u16* Ab = (z ? A1 : A) + (size_t)(by * 128) * lda;
  const u16* Bb = (z ? B1 : B) + (size_t)(bx * 128) * ldb;

  f32x4 zero = {0.0f, 0.0f, 0.0f, 0.0f};
  f32x4 acc[4][4];
#pragma unroll
  for (int i = 0; i < 4; ++i)
#pragma unroll
    for (int j = 0; j < 4; ++j) acc[i][j] = zero;

  const int sr = tid >> 3;                        // 0..31 (row within 32-row group)
  const int scL = (tid & 7) << 3;                 // LDS dst col (lane*16B forced)
  const int scG = ((tid & 7) ^ (sr & 7)) << 3;    // swizzled global col granule

  // Hoisted loop-invariant LDS fragment byte offsets (R5):
  // logical granule gl = (kk>>3)+(lane>>4); physical = gl ^ (row&7);
  // row&7 == lane&7 for all fragment rows; kk=32 flips byte 64.
  const int l7 = lane & 7, l16 = lane >> 4;
  const int p0b = (l16 ^ l7) << 4;
  const int offA0 = (wr + ar) * 128 + p0b;
  const int offB0 = (wc + ar) * 128 + p0b;
  const char* sAc = (const char*)sA;
  const char* sBc = (const char*)sB;

  for (int k0 = 0; k0 < K; k0 += 64) {
#pragma unroll
    for (int it = 0; it < 4; ++it) {
      int r = it * 32 + sr;
      __builtin_amdgcn_global_load_lds(
          (__attribute__((address_space(1))) void*)(Ab + (size_t)r * lda + k0 + scG),
          (__attribute__((address_space(3))) void*)(sA + r * 64 + scL), 16, 0, 0);
    }
#pragma unroll
    for (int it = 0; it < 4; ++it) {
      int r = it * 32 + sr;
      __builtin_amdgcn_global_load_lds(
          (__attribute__((address_space(1))) void*)(Bb + (size_t)r * ldb + k0 + scG),
          (__attribute__((address_space(3))) void*)(sB + r * 64 + scL), 16, 0, 0);
    }
    __syncthreads();
#pragma unroll
    for (int half = 0; half < 2; ++half) {
      const int px = half ? 64 : 0;
      bf16x8 af[4], bfr[4];
#pragma unroll
      for (int t = 0; t < 4; ++t)
        af[t] = *(const bf16x8*)(sAc + ((offA0 ^ px) + t * 2048));
#pragma unroll
      for (int t = 0; t < 4; ++t)
        bfr[t] = *(const bf16x8*)(sBc + ((offB0 ^ px) + t * 2048));
#pragma unroll
      for (int tm = 0; tm < 4; ++tm)
#pragma unroll
        for (int tn = 0; tn < 4; ++tn)
          acc[tm][tn] = __builtin_amdgcn_mfma_f32_16x16x32_bf16(
              af[tm], bfr[tn], acc[tm][tn], 0, 0, 0);
    }
    __syncthreads();
  }

  // Epilogue. C/D layout (m89): row=(lane>>4)*4+reg, col=lane&15.
  const int qr = (lane >> 4) * 4;
  const int qc = lane & 15;

  if constexpr (EPI == 0) {
#pragma unroll
    for (int tm = 0; tm < 4; ++tm)
#pragma unroll
      for (int r = 0; r < 4; ++r) {
        int row = by * 128 + wr + tm * 16 + qr + r;
#pragma unroll
        for (int tn = 0; tn < 4; ++tn) {
          int col = bx * 128 + wc + tn * 16 + qc;
          float sc = (col < 1024) ? sq : sk;
          outb[(size_t)row * ldc + col] = f2b(acc[tm][tn][r] * sc);
        }
      }
  } else if constexpr (EPI == 1) {
    const bool top = (by < 32);
    const bool left = (bx < 32);
    u16* pdst = nullptr;
    if (top && !left) pdst = Pcq;
    if (!top && left) pdst = Pqc;
    const int growb = by * 128 + wr;
    const int rbase = growb - (top ? 0 : 4096);
    const int cbase = bx * 128 + wc - (left ? 0 : 4096);
#pragma unroll
    for (int tm = 0; tm < 4; ++tm) {
      float e[4][4];
      float rsum[4] = {0.f, 0.f, 0.f, 0.f};
#pragma unroll
      for (int tn = 0; tn < 4; ++tn)
#pragma unroll
        for (int r = 0; r < 4; ++r) {
          e[tn][r] = exp2_hw(acc[tm][tn][r]);  // scores pre-scaled by log2(e)
          rsum[r] += e[tn][r];
        }
#pragma unroll
      for (int r = 0; r < 4; ++r) {
        float v = rsum[r];
        v += __shfl_xor(v, 1);
        v += __shfl_xor(v, 2);
        v += __shfl_xor(v, 4);
        v += __shfl_xor(v, 8);
        if ((lane & 15) == 0)
          atomicAdd(&rowsum[growb + tm * 16 + qr + r], v);
      }
      if (pdst) {
#pragma unroll
        for (int tn = 0; tn < 4; ++tn)
#pragma unroll
          for (int r = 0; r < 4; ++r) {
            int row = rbase + tm * 16 + qr + r;
            pdst[(size_t)row * 4096 + cbase + tn * 16 + qc] = f2b(e[tn][r]);
          }
      }
    }
  } else if constexpr (EPI == 4) {
    float* of = z ? outf1 : outf;
    const float* rsz = z ? rs1 : rs;
#pragma unroll
    for (int tm = 0; tm < 4; ++tm)
#pragma unroll
      for (int r = 0; r < 4; ++r) {
        int row = by * 128 + wr + tm * 16 + qr + r;
        float inv = 1.0f / rsz[row];
#pragma unroll
        for (int tn = 0; tn < 4; ++tn) {
          int col = bx * 128 + wc + tn * 16 + qc;
          of[(size_t)row * ldc + col] = acc[tm][tn][r] * inv;
        }
      }
  } else {  // EPI 5
    u16* ob = z ? outb1 : outb;
#pragma unroll
    for (int tm = 0; tm < 4; ++tm)
#pragma unroll
      for (int r = 0; r < 4; ++r) {
        int row = by * 128 + wr + tm * 16 + qr + r;
#pragma unroll
        for (int tn = 0; tn < 4; ++tn) {
          int col = bx * 128 + wc + tn * 16 + qc;
          ob[(size_t)row * ldc + col] = f2b(acc[tm][tn][r]);
        }
      }
  }
}

// ---------------- launcher ----------------

extern "C" void kernel_launch(void* const* d_in, const int* in_sizes, int n_in,
                              void* d_out, int out_size, void* d_ws, size_t ws_size,
                              hipStream_t stream) {
  (void)in_sizes; (void)n_in; (void)out_size; (void)ws_size;
  const float* query = (const float*)d_in[0];
  const float* s     = (const float*)d_in[1];
  const float* tg    = (const float*)d_in[2];
  const float* Wqkv  = (const float*)d_in[3];
  const float* Wps   = (const float*)d_in[4];
  const float* Wpq   = (const float*)d_in[5];
  float* out = (float*)d_out;

  char* ws = (char*)d_ws;
  u16* cB     = (u16*)ws; ws += (size_t)8192 * 1024 * 2;   // [s+tg ; query] bf16
  u16* sBf    = (u16*)ws; ws += (size_t)4096 * 1024 * 2;   // s bf16
  u16* qks    = (u16*)ws; ws += (size_t)8192 * 2048 * 2;   // [q*SCALE*LOG2E | k*SCALE]
  u16* WqkB   = (u16*)ws; ws += (size_t)2048 * 1024 * 2;
  u16* WpsB   = (u16*)ws; ws += (size_t)1024 * 1024 * 2;
  u16* WpqB   = (u16*)ws; ws += (size_t)1024 * 1024 * 2;
  u16* VsT    = (u16*)ws; ws += (size_t)1024 * 4096 * 2;   // (Wps@query^T)
  u16* VqT    = (u16*)ws; ws += (size_t)1024 * 4096 * 2;   // (Wpq@s^T)
  u16* Pcq    = (u16*)ws; ws += (size_t)4096 * 4096 * 2;
  u16* Pqc    = (u16*)ws; ws += (size_t)4096 * 4096 * 2;
  float* rowsum = (float*)ws;  // 8192 floats

  const u16* qBf = cB + (size_t)4096 * 1024;  // query bf16 rows of cB

  const float SCALE = 0.17677669529663687f;   // 1024^-0.25
  const float LOG2E = 1.4426950408889634f;

  (void)hipMemsetAsync(rowsum, 0, 8192 * sizeof(float), stream);
  prep_all<<<6144, 256, 0, stream>>>(query, s, tg, Wqkv, Wps, Wpq,
                                     cB, sBf, WqkB, WpsB, WpqB);

  // V'^T pair: VsT = Wps@query^T, VqT = Wpq@s^T  (M=1024,N=4096,K=1024)
  gemm_bt<5><<<dim3(32, 8, 2), 256, 0, stream>>>(
      WpsB, WpqB, qBf, sBf, 1024, 1024, 1024, 4096,
      VsT, VqT, nullptr, nullptr, 0.f, 0.f,
      nullptr, nullptr, nullptr, nullptr, nullptr);
  // GEMM1: qks[8192,2048] = cB @ WqkB^T; q cols scaled SCALE*LOG2E, k cols SCALE
  gemm_bt<0><<<dim3(16, 64), 256, 0, stream>>>(
      cB, nullptr, WqkB, nullptr, 1024, 1024, 1024, 2048,
      qks, nullptr, nullptr, nullptr, SCALE * LOG2E, SCALE,
      nullptr, nullptr, nullptr, nullptr, nullptr);
  // GEMM2: scores (8192x8192) -> 2^score quadrants (bf16) + row sums
  gemm_bt<1><<<dim3(64, 64), 256, 0, stream>>>(
      qks, nullptr, qks + 1024, nullptr, 2048, 2048, 1024, 0,
      nullptr, nullptr, nullptr, nullptr, 0.f, 0.f,
      nullptr, nullptr, Pcq, Pqc, rowsum);
  // PV (z-batched), fp32 straight to d_out: x_s = (Pcq@VsT^T)/rs ; x_q = (Pqc@VqT^T)/rs
  gemm_bt<4><<<dim3(8, 32, 2), 256, 0, stream>>>(
      Pcq, Pqc, VsT, VqT, 4096, 4096, 4096, 1024,
      nullptr, nullptr, out, out + (size_t)4096 * 1024, 0.f, 0.f,
      rowsum, rowsum + 4096, nullptr, nullptr, nullptr);
}